// Round 1
// baseline (310.491 us; speedup 1.0000x reference)
//
#include <hip/hip_runtime.h>

// Causal flash attention fwd: B=4,H=16,S=2048,D=64. fp32 I/O, bf16 MFMA compute.
// MFMA 16x16x32 bf16. Layouts (HW-verified, learn_hip m89/m91/m120):
//   A[m=lane&15][k=quad*8+j], B[k=quad*8+j][n=lane&15],
//   C/D: col=lane&15, row=quad*4+reg.
// R5: SWAPPED QK^T (S^T = mfma(K,Q)) so each lane holds a full 16-kv slice of P
// for ONE q-row (q=lcol). kv dimension is reordered by
//   pi(32h+8Q+j) = 16*(2h+(j>>2)) + 4Q + (j&3)
// so the lane's 16 exp values map EXACTLY onto its own PV A-fragment slots:
// P never touches LDS, zero cross-lane ops (was 16 ds_write_b16 + 4 ds_read_b64
// + lgkmcnt roundtrip per q-tile). V is staged at column sigma(kv) =
// (kv&0x23)|((kv&0xC)<<1)|((kv&0x10)>>2) = pi^-1, a free constant address bit-
// shuffle, so V's B-frag k-order matches. Pl LDS buffer deleted (52.2->34.8 KB),
// prefetch regs packed to bf16 at load (32->16 VGPRs), launch_bounds(256,4).
// Retained from R4: complementary q-tile pairing (uniform 33 tiles/block),
// double-buffered K/V LDS, ONE barrier/tile, register prefetch one tile ahead.

typedef short bf16x4 __attribute__((ext_vector_type(4)));
typedef short bf16x8 __attribute__((ext_vector_type(8)));
typedef float f32x4  __attribute__((ext_vector_type(4)));

#define S_LEN 2048
#define D_DIM 64
#define BM 64
#define BN 64
#define KSTR 68
#define VSTR 68
#define SC_LOG2E 0.18033688011112042f   // (1/8) * log2(e)

// pack two fp32 -> bf16x2 dword by truncation (1 v_perm_b32)
__device__ __forceinline__ unsigned pk2(float lo, float hi) {
    return __builtin_amdgcn_perm(__builtin_bit_cast(unsigned, hi),
                                 __builtin_bit_cast(unsigned, lo), 0x07060302u);
}

__device__ __forceinline__ bf16x8 ldfrag(const short* p) {
    bf16x4 lo = *(const bf16x4*)(p);
    bf16x4 hi = *(const bf16x4*)(p + 4);
    bf16x8 r;
    r[0] = lo[0]; r[1] = lo[1]; r[2] = lo[2]; r[3] = lo[3];
    r[4] = hi[0]; r[5] = hi[1]; r[6] = hi[2]; r[7] = hi[3];
    return r;
}

__device__ __forceinline__ bf16x8 mk8(unsigned u0, unsigned u1, unsigned u2, unsigned u3) {
    union { unsigned u[4]; bf16x8 v; } r;
    r.u[0] = u0; r.u[1] = u1; r.u[2] = u2; r.u[3] = u3;
    return r.v;
}

__global__ __launch_bounds__(256, 4) void fattn_kernel(
    const float* __restrict__ Q, const float* __restrict__ K,
    const float* __restrict__ V, float* __restrict__ O)
{
    __shared__ short Kl[2][BN * KSTR];        // 17408 B
    __shared__ short Vt[2][D_DIM * VSTR];     // 17408 B (V transposed [d][sigma(kv)])

    const int t    = threadIdx.x;
    const int wid  = t >> 6;
    const int lane = t & 63;
    const int quad = lane >> 4;
    const int lcol = lane & 15;

    // paired q-tiles: A = blockIdx.x (short), B = 31-blockIdx.x (long)
    const int na  = blockIdx.x + 1;           // 1..16
    const int nb  = 32 - blockIdx.x;          // 32..17  (nb > na always)
    const int q0a = blockIdx.x * BM;
    const int q0b = (31 - blockIdx.x) * BM;

    const int bh = blockIdx.y;
    const size_t base = (size_t)bh * (S_LEN * D_DIM);
    const float* Qh = Q + base;
    const float* Kh = K + base;
    const float* Vh = V + base;
    float*       Oh = O + base;

    // staging coordinates
    const int skv = t >> 2;            // K: row 0..63
    const int sd  = (t & 3) * 16;      // K: 16-col block
    const int vkv = (t & 31) * 2;      // V: row pair
    const int vdd = (t >> 5) * 8;      // V: 8-col block
    // sigma(kv): bit shuffle [c1 c0 Q1 Q0 r1 r0] -> [c1 Q1 Q0 c0 r1 r0]
    const int vkvp = (vkv & 0x23) | ((vkv & 0x0C) << 1) | ((vkv & 0x10) >> 2);

    // ---- Q fragments for both q-tiles (bf16, d = quad*8+j per mfma half) ----
    bf16x8 aqA0, aqA1, aqB0, aqB1;
    {
        const float* qp = Qh + (size_t)(q0a + wid * 16 + lcol) * D_DIM;
        float4 a = *(const float4*)(qp + quad * 8);
        float4 b = *(const float4*)(qp + quad * 8 + 4);
        float4 c = *(const float4*)(qp + 32 + quad * 8);
        float4 d = *(const float4*)(qp + 32 + quad * 8 + 4);
        aqA0 = mk8(pk2(a.x, a.y), pk2(a.z, a.w), pk2(b.x, b.y), pk2(b.z, b.w));
        aqA1 = mk8(pk2(c.x, c.y), pk2(c.z, c.w), pk2(d.x, d.y), pk2(d.z, d.w));
    }
    {
        const float* qp = Qh + (size_t)(q0b + wid * 16 + lcol) * D_DIM;
        float4 a = *(const float4*)(qp + quad * 8);
        float4 b = *(const float4*)(qp + quad * 8 + 4);
        float4 c = *(const float4*)(qp + 32 + quad * 8);
        float4 d = *(const float4*)(qp + 32 + quad * 8 + 4);
        aqB0 = mk8(pk2(a.x, a.y), pk2(a.z, a.w), pk2(b.x, b.y), pk2(b.z, b.w));
        aqB1 = mk8(pk2(c.x, c.y), pk2(c.z, c.w), pk2(d.x, d.y), pk2(d.z, d.w));
    }

    f32x4 oA[4], oB[4];
    #pragma unroll
    for (int nt = 0; nt < 4; ++nt) {
        oA[nt] = f32x4{0.f, 0.f, 0.f, 0.f};
        oB[nt] = f32x4{0.f, 0.f, 0.f, 0.f};
    }
    float lpA = 0.f, lpB = 0.f;        // per-lane row-sum for q = wid*16+lcol
    const int qrel  = wid * 16 + lcol; // q row this lane owns in softmax phase
    const int row_l = wid * 16 + quad * 4;  // q rows this lane owns in O

    // prefetch registers, already packed to bf16 (16 dwords)
    unsigned kq0, kq1, kq2, kq3, kq4, kq5, kq6, kq7;
    unsigned vq0, vq1, vq2, vq3, vq4, vq5, vq6, vq7;

#define PREFETCH(tl) do {                                                     \
        const float* kp_ = Kh + (size_t)((tl) * BN + skv) * D_DIM + sd;       \
        const float4 ka_ = *(const float4*)(kp_);                             \
        const float4 kb_ = *(const float4*)(kp_ + 4);                         \
        const float4 kc_ = *(const float4*)(kp_ + 8);                         \
        const float4 kd_ = *(const float4*)(kp_ + 12);                        \
        kq0 = pk2(ka_.x, ka_.y); kq1 = pk2(ka_.z, ka_.w);                     \
        kq2 = pk2(kb_.x, kb_.y); kq3 = pk2(kb_.z, kb_.w);                     \
        kq4 = pk2(kc_.x, kc_.y); kq5 = pk2(kc_.z, kc_.w);                     \
        kq6 = pk2(kd_.x, kd_.y); kq7 = pk2(kd_.z, kd_.w);                     \
        const float* vp_ = Vh + (size_t)((tl) * BN + vkv) * D_DIM + vdd;      \
        const float4 va_ = *(const float4*)(vp_);                             \
        const float4 vb_ = *(const float4*)(vp_ + 4);                         \
        const float4 vc_ = *(const float4*)(vp_ + D_DIM);                     \
        const float4 ve_ = *(const float4*)(vp_ + D_DIM + 4);                 \
        vq0 = pk2(va_.x, vc_.x); vq1 = pk2(va_.y, vc_.y);                     \
        vq2 = pk2(va_.z, vc_.z); vq3 = pk2(va_.w, vc_.w);                     \
        vq4 = pk2(vb_.x, ve_.x); vq5 = pk2(vb_.y, ve_.y);                     \
        vq6 = pk2(vb_.z, ve_.z); vq7 = pk2(vb_.w, ve_.w);                     \
    } while (0)

#define STAGE(KB, VB) do {                                                    \
        short* kd_ = (KB) + skv * KSTR + sd;                                  \
        *(uint2*)(kd_)      = make_uint2(kq0, kq1);                           \
        *(uint2*)(kd_ + 4)  = make_uint2(kq2, kq3);                           \
        *(uint2*)(kd_ + 8)  = make_uint2(kq4, kq5);                           \
        *(uint2*)(kd_ + 12) = make_uint2(kq6, kq7);                           \
        short* vd_ = (VB) + vkvp;                                             \
        *(unsigned*)(vd_ + (vdd + 0) * VSTR) = vq0;                           \
        *(unsigned*)(vd_ + (vdd + 1) * VSTR) = vq1;                           \
        *(unsigned*)(vd_ + (vdd + 2) * VSTR) = vq2;                           \
        *(unsigned*)(vd_ + (vdd + 3) * VSTR) = vq3;                           \
        *(unsigned*)(vd_ + (vdd + 4) * VSTR) = vq4;                           \
        *(unsigned*)(vd_ + (vdd + 5) * VSTR) = vq5;                           \
        *(unsigned*)(vd_ + (vdd + 6) * VSTR) = vq6;                           \
        *(unsigned*)(vd_ + (vdd + 7) * VSTR) = vq7;                           \
    } while (0)

// softmax + in-register P pack: lane holds e[ct][r] = P[q=lcol][16ct+4quad+r];
// A-frag slot (h, j) needs P[q][pi(32h+8quad+j)] = e[2h+(j>>2)][j&3]  ->
// ap0 = bf16{e[0][0..3], e[1][0..3]},  ap1 = bf16{e[2][0..3], e[3][0..3]}.
#define SOFTMAX_PACK(sS, lp, diag, ap0, ap1) do {                             \
        unsigned pb_[8];                                                      \
        _Pragma("unroll")                                                     \
        for (int ct = 0; ct < 4; ++ct) {                                      \
            float e_[4];                                                      \
            _Pragma("unroll")                                                 \
            for (int r = 0; r < 4; ++r) {                                     \
                float x_ = (sS)[ct][r] * SC_LOG2E;                            \
                if ((diag) && (ct * 16 + quad * 4 + r > qrel))                \
                    x_ = -__builtin_inff();                                   \
                e_[r] = __builtin_amdgcn_exp2f(x_);                           \
                (lp) += e_[r];                                                \
            }                                                                 \
            pb_[2 * ct]     = pk2(e_[0], e_[1]);                              \
            pb_[2 * ct + 1] = pk2(e_[2], e_[3]);                              \
        }                                                                     \
        (ap0) = mk8(pb_[0], pb_[1], pb_[2], pb_[3]);                          \
        (ap1) = mk8(pb_[4], pb_[5], pb_[6], pb_[7]);                          \
    } while (0)

    PREFETCH(0);
    STAGE(Kl[0], Vt[0]);
    PREFETCH(1);
    __syncthreads();

    for (int tile = 0; tile < nb; ++tile) {
        const int cur = tile & 1;
        const short* Kb = Kl[cur];
        const short* Vb = Vt[cur];
        const bool doA = (tile < na);

        // ---- swapped QK^T: S^T[kv][q] = mfma(K_frag, Q_frag), K frags shared ----
        f32x4 sA[4], sB[4];
        #pragma unroll
        for (int ct = 0; ct < 4; ++ct) {
            const short* kp0 = &Kb[(ct * 16 + lcol) * KSTR + quad * 8];
            const bf16x8 b0 = ldfrag(kp0);        // d = quad*8+j       (k half 0)
            const bf16x8 b1 = ldfrag(kp0 + 32);   // d = 32+quad*8+j    (k half 1)
            f32x4 z = f32x4{0.f, 0.f, 0.f, 0.f};
            z = __builtin_amdgcn_mfma_f32_16x16x32_bf16(b0, aqB0, z, 0, 0, 0);
            z = __builtin_amdgcn_mfma_f32_16x16x32_bf16(b1, aqB1, z, 0, 0, 0);
            sB[ct] = z;
            if (doA) {
                f32x4 y = f32x4{0.f, 0.f, 0.f, 0.f};
                y = __builtin_amdgcn_mfma_f32_16x16x32_bf16(b0, aqA0, y, 0, 0, 0);
                y = __builtin_amdgcn_mfma_f32_16x16x32_bf16(b1, aqA1, y, 0, 0, 0);
                sA[ct] = y;
            }
        }

        // ---- softmax numerators, packed straight into PV A-fragments ----
        bf16x8 apA0, apA1, apB0, apB1;
        SOFTMAX_PACK(sB, lpB, tile == nb - 1, apB0, apB1);
        if (doA) SOFTMAX_PACK(sA, lpA, tile == na - 1, apA0, apA1);

        // ---- O += P V : shared V fragments (kv-slot order = sigma layout) ----
        #pragma unroll
        for (int nt = 0; nt < 4; ++nt) {
            const short* vp0 = &Vb[(nt * 16 + lcol) * VSTR + quad * 8];
            const bf16x8 v0 = ldfrag(vp0);
            const bf16x8 v1 = ldfrag(vp0 + 32);
            oB[nt] = __builtin_amdgcn_mfma_f32_16x16x32_bf16(apB0, v0, oB[nt], 0, 0, 0);
            oB[nt] = __builtin_amdgcn_mfma_f32_16x16x32_bf16(apB1, v1, oB[nt], 0, 0, 0);
            if (doA) {
                oA[nt] = __builtin_amdgcn_mfma_f32_16x16x32_bf16(apA0, v0, oA[nt], 0, 0, 0);
                oA[nt] = __builtin_amdgcn_mfma_f32_16x16x32_bf16(apA1, v1, oA[nt], 0, 0, 0);
            }
        }

        // ---- stage next tile into other buffer; prefetch tile+2 ----
        if (tile + 1 < nb) {
            STAGE(Kl[cur ^ 1], Vt[cur ^ 1]);
            if (tile + 2 < nb) PREFETCH(tile + 2);
        }
        __syncthreads();
    }

    // ---- epilogue: l lives per-lane for q=lcol; reduce across quads only ----
    lpA += __shfl_xor(lpA, 16, 64);
    lpA += __shfl_xor(lpA, 32, 64);
    lpB += __shfl_xor(lpB, 16, 64);
    lpB += __shfl_xor(lpB, 32, 64);
    #pragma unroll
    for (int r = 0; r < 4; ++r) {
        // O rows this lane stores are q = row_l + r; their l is held by lane
        // with lcol = quad*4+r (any quad after the reduce -> use lane quad*4+r)
        const float invA = 1.0f / __shfl(lpA, quad * 4 + r, 64);
        const float invB = 1.0f / __shfl(lpB, quad * 4 + r, 64);
        float* opA = Oh + (size_t)(q0a + row_l + r) * D_DIM;
        float* opB = Oh + (size_t)(q0b + row_l + r) * D_DIM;
        #pragma unroll
        for (int nt = 0; nt < 4; ++nt) {
            opA[nt * 16 + lcol] = oA[nt][r] * invA;
            opB[nt * 16 + lcol] = oB[nt][r] * invB;
        }
    }
}

extern "C" void kernel_launch(void* const* d_in, const int* in_sizes, int n_in,
                              void* d_out, int out_size, void* d_ws, size_t ws_size,
                              hipStream_t stream) {
    const float* Q = (const float*)d_in[0];
    const float* K = (const float*)d_in[1];
    const float* V = (const float*)d_in[2];
    float*       O = (float*)d_out;
    dim3 grid(S_LEN / BM / 2, 4 * 16);   // 16 complementary q-pairs x 64 heads
    fattn_kernel<<<grid, 256, 0, stream>>>(Q, K, V, O);
}

// Round 2
// 272.993 us; speedup vs baseline: 1.1374x; 1.1374x over previous
//
#include <hip/hip_runtime.h>

// Causal flash attention fwd: B=4,H=16,S=2048,D=64. fp32 I/O, bf16 MFMA compute.
// MFMA 16x16x32 bf16. Layouts (HW-verified, learn_hip m89/m91/m120):
//   A[m=lane&15][k=quad*8+j], B[k=quad*8+j][n=lane&15],
//   C/D: col=lane&15, row=quad*4+reg.
// R6: SPILL FIX. R5's shared-K structure had peak liveness ~150 regs > the 128
// unified VGPR+AGPR cap of launch_bounds(256,4) -> ~3 dwords/iter scratch spill
// (WRITE_SIZE 105 MB vs 33.5 MB O; scratch reloads = global-latency stalls on
// the per-tile critical path). Fix: process q-tile B then q-tile A as two
// sequential phases per kv-tile so sA/sB (16), apA/apB (8) and K/V fragments
// (8) never coexist -> peak ~124 regs, spill-free at (256,4), preserving
// 4 blocks/CU residency. Cost: K/V frags re-read from LDS for phase A (LDS is
// conflict-free and SIMDs 86% idle). Plus T5 s_setprio(1) around MFMA clusters.
// Retained from R5: swapped QK^T with in-register P (pi/sigma kv reorder, zero
// LDS for P), complementary q-tile pairing, double-buffered K/V LDS, ONE
// barrier/tile, register prefetch one tile ahead, bf16-packed prefetch regs.

typedef short bf16x4 __attribute__((ext_vector_type(4)));
typedef short bf16x8 __attribute__((ext_vector_type(8)));
typedef float f32x4  __attribute__((ext_vector_type(4)));

#define S_LEN 2048
#define D_DIM 64
#define BM 64
#define BN 64
#define KSTR 68
#define VSTR 68
#define SC_LOG2E 0.18033688011112042f   // (1/8) * log2(e)

// pack two fp32 -> bf16x2 dword by truncation (1 v_perm_b32)
__device__ __forceinline__ unsigned pk2(float lo, float hi) {
    return __builtin_amdgcn_perm(__builtin_bit_cast(unsigned, hi),
                                 __builtin_bit_cast(unsigned, lo), 0x07060302u);
}

__device__ __forceinline__ bf16x8 ldfrag(const short* p) {
    bf16x4 lo = *(const bf16x4*)(p);
    bf16x4 hi = *(const bf16x4*)(p + 4);
    bf16x8 r;
    r[0] = lo[0]; r[1] = lo[1]; r[2] = lo[2]; r[3] = lo[3];
    r[4] = hi[0]; r[5] = hi[1]; r[6] = hi[2]; r[7] = hi[3];
    return r;
}

__device__ __forceinline__ bf16x8 mk8(unsigned u0, unsigned u1, unsigned u2, unsigned u3) {
    union { unsigned u[4]; bf16x8 v; } r;
    r.u[0] = u0; r.u[1] = u1; r.u[2] = u2; r.u[3] = u3;
    return r.v;
}

__global__ __launch_bounds__(256, 4) void fattn_kernel(
    const float* __restrict__ Q, const float* __restrict__ K,
    const float* __restrict__ V, float* __restrict__ O)
{
    __shared__ short Kl[2][BN * KSTR];        // 17408 B
    __shared__ short Vt[2][D_DIM * VSTR];     // 17408 B (V transposed [d][sigma(kv)])

    const int t    = threadIdx.x;
    const int wid  = t >> 6;
    const int lane = t & 63;
    const int quad = lane >> 4;
    const int lcol = lane & 15;

    // paired q-tiles: A = blockIdx.x (short), B = 31-blockIdx.x (long)
    const int na  = blockIdx.x + 1;           // 1..16
    const int nb  = 32 - blockIdx.x;          // 32..17  (nb > na always)
    const int q0a = blockIdx.x * BM;
    const int q0b = (31 - blockIdx.x) * BM;

    const int bh = blockIdx.y;
    const size_t base = (size_t)bh * (S_LEN * D_DIM);
    const float* Qh = Q + base;
    const float* Kh = K + base;
    const float* Vh = V + base;
    float*       Oh = O + base;

    // staging coordinates
    const int skv = t >> 2;            // K: row 0..63
    const int sd  = (t & 3) * 16;      // K: 16-col block
    const int vkv = (t & 31) * 2;      // V: row pair
    const int vdd = (t >> 5) * 8;      // V: 8-col block
    // sigma(kv): bit shuffle [c1 c0 Q1 Q0 r1 r0] -> [c1 Q1 Q0 c0 r1 r0]
    const int vkvp = (vkv & 0x23) | ((vkv & 0x0C) << 1) | ((vkv & 0x10) >> 2);

    // ---- Q fragments for both q-tiles (bf16, d = quad*8+j per mfma half) ----
    bf16x8 aqA0, aqA1, aqB0, aqB1;
    {
        const float* qp = Qh + (size_t)(q0a + wid * 16 + lcol) * D_DIM;
        float4 a = *(const float4*)(qp + quad * 8);
        float4 b = *(const float4*)(qp + quad * 8 + 4);
        float4 c = *(const float4*)(qp + 32 + quad * 8);
        float4 d = *(const float4*)(qp + 32 + quad * 8 + 4);
        aqA0 = mk8(pk2(a.x, a.y), pk2(a.z, a.w), pk2(b.x, b.y), pk2(b.z, b.w));
        aqA1 = mk8(pk2(c.x, c.y), pk2(c.z, c.w), pk2(d.x, d.y), pk2(d.z, d.w));
    }
    {
        const float* qp = Qh + (size_t)(q0b + wid * 16 + lcol) * D_DIM;
        float4 a = *(const float4*)(qp + quad * 8);
        float4 b = *(const float4*)(qp + quad * 8 + 4);
        float4 c = *(const float4*)(qp + 32 + quad * 8);
        float4 d = *(const float4*)(qp + 32 + quad * 8 + 4);
        aqB0 = mk8(pk2(a.x, a.y), pk2(a.z, a.w), pk2(b.x, b.y), pk2(b.z, b.w));
        aqB1 = mk8(pk2(c.x, c.y), pk2(c.z, c.w), pk2(d.x, d.y), pk2(d.z, d.w));
    }

    f32x4 oA[4], oB[4];
    #pragma unroll
    for (int nt = 0; nt < 4; ++nt) {
        oA[nt] = f32x4{0.f, 0.f, 0.f, 0.f};
        oB[nt] = f32x4{0.f, 0.f, 0.f, 0.f};
    }
    float lpA = 0.f, lpB = 0.f;        // per-lane row-sum for q = wid*16+lcol
    const int qrel  = wid * 16 + lcol; // q row this lane owns in softmax phase
    const int row_l = wid * 16 + quad * 4;  // q rows this lane owns in O

    // prefetch registers, already packed to bf16 (16 dwords)
    unsigned kq0, kq1, kq2, kq3, kq4, kq5, kq6, kq7;
    unsigned vq0, vq1, vq2, vq3, vq4, vq5, vq6, vq7;

#define PREFETCH(tl) do {                                                     \
        const float* kp_ = Kh + (size_t)((tl) * BN + skv) * D_DIM + sd;       \
        const float4 ka_ = *(const float4*)(kp_);                             \
        const float4 kb_ = *(const float4*)(kp_ + 4);                         \
        const float4 kc_ = *(const float4*)(kp_ + 8);                         \
        const float4 kd_ = *(const float4*)(kp_ + 12);                        \
        kq0 = pk2(ka_.x, ka_.y); kq1 = pk2(ka_.z, ka_.w);                     \
        kq2 = pk2(kb_.x, kb_.y); kq3 = pk2(kb_.z, kb_.w);                     \
        kq4 = pk2(kc_.x, kc_.y); kq5 = pk2(kc_.z, kc_.w);                     \
        kq6 = pk2(kd_.x, kd_.y); kq7 = pk2(kd_.z, kd_.w);                     \
        const float* vp_ = Vh + (size_t)((tl) * BN + vkv) * D_DIM + vdd;      \
        const float4 va_ = *(const float4*)(vp_);                             \
        const float4 vb_ = *(const float4*)(vp_ + 4);                         \
        const float4 vc_ = *(const float4*)(vp_ + D_DIM);                     \
        const float4 ve_ = *(const float4*)(vp_ + D_DIM + 4);                 \
        vq0 = pk2(va_.x, vc_.x); vq1 = pk2(va_.y, vc_.y);                     \
        vq2 = pk2(va_.z, vc_.z); vq3 = pk2(va_.w, vc_.w);                     \
        vq4 = pk2(vb_.x, ve_.x); vq5 = pk2(vb_.y, ve_.y);                     \
        vq6 = pk2(vb_.z, ve_.z); vq7 = pk2(vb_.w, ve_.w);                     \
    } while (0)

#define STAGE(KB, VB) do {                                                    \
        short* kd_ = (KB) + skv * KSTR + sd;                                  \
        *(uint2*)(kd_)      = make_uint2(kq0, kq1);                           \
        *(uint2*)(kd_ + 4)  = make_uint2(kq2, kq3);                           \
        *(uint2*)(kd_ + 8)  = make_uint2(kq4, kq5);                           \
        *(uint2*)(kd_ + 12) = make_uint2(kq6, kq7);                           \
        short* vd_ = (VB) + vkvp;                                             \
        *(unsigned*)(vd_ + (vdd + 0) * VSTR) = vq0;                           \
        *(unsigned*)(vd_ + (vdd + 1) * VSTR) = vq1;                           \
        *(unsigned*)(vd_ + (vdd + 2) * VSTR) = vq2;                           \
        *(unsigned*)(vd_ + (vdd + 3) * VSTR) = vq3;                           \
        *(unsigned*)(vd_ + (vdd + 4) * VSTR) = vq4;                           \
        *(unsigned*)(vd_ + (vdd + 5) * VSTR) = vq5;                           \
        *(unsigned*)(vd_ + (vdd + 6) * VSTR) = vq6;                           \
        *(unsigned*)(vd_ + (vdd + 7) * VSTR) = vq7;                           \
    } while (0)

// softmax + in-register P pack: lane holds e[ct][r] = P[q=lcol][16ct+4quad+r];
// A-frag slot (h, j) needs P[q][pi(32h+8quad+j)] = e[2h+(j>>2)][j&3]  ->
// ap0 = bf16{e[0][0..3], e[1][0..3]},  ap1 = bf16{e[2][0..3], e[3][0..3]}.
#define SOFTMAX_PACK(sS, lp, diag, ap0, ap1) do {                             \
        unsigned pb_[8];                                                      \
        _Pragma("unroll")                                                     \
        for (int ct = 0; ct < 4; ++ct) {                                      \
            float e_[4];                                                      \
            _Pragma("unroll")                                                 \
            for (int r = 0; r < 4; ++r) {                                     \
                float x_ = (sS)[ct][r] * SC_LOG2E;                            \
                if ((diag) && (ct * 16 + quad * 4 + r > qrel))                \
                    x_ = -__builtin_inff();                                   \
                e_[r] = __builtin_amdgcn_exp2f(x_);                           \
                (lp) += e_[r];                                                \
            }                                                                 \
            pb_[2 * ct]     = pk2(e_[0], e_[1]);                              \
            pb_[2 * ct + 1] = pk2(e_[2], e_[3]);                              \
        }                                                                     \
        (ap0) = mk8(pb_[0], pb_[1], pb_[2], pb_[3]);                          \
        (ap1) = mk8(pb_[4], pb_[5], pb_[6], pb_[7]);                          \
    } while (0)

// one q-tile phase: QK^T (swapped) -> softmax pack -> PV accumulate.
// All MFMA inputs/results are phase-local so A/B phases share registers.
#define QTILE_PHASE(aq0, aq1, oACC, lp, diagCond) do {                        \
        f32x4 s_[4];                                                          \
        __builtin_amdgcn_s_setprio(1);                                        \
        _Pragma("unroll")                                                     \
        for (int ct = 0; ct < 4; ++ct) {                                      \
            const short* kp_ = &Kb[(ct * 16 + lcol) * KSTR + quad * 8];       \
            const bf16x8 b0_ = ldfrag(kp_);                                   \
            const bf16x8 b1_ = ldfrag(kp_ + 32);                              \
            f32x4 z_ = f32x4{0.f, 0.f, 0.f, 0.f};                             \
            z_ = __builtin_amdgcn_mfma_f32_16x16x32_bf16(b0_, aq0, z_, 0, 0, 0); \
            z_ = __builtin_amdgcn_mfma_f32_16x16x32_bf16(b1_, aq1, z_, 0, 0, 0); \
            s_[ct] = z_;                                                      \
        }                                                                     \
        __builtin_amdgcn_s_setprio(0);                                        \
        bf16x8 ap0_, ap1_;                                                    \
        SOFTMAX_PACK(s_, lp, diagCond, ap0_, ap1_);                           \
        __builtin_amdgcn_s_setprio(1);                                        \
        _Pragma("unroll")                                                     \
        for (int nt = 0; nt < 4; ++nt) {                                      \
            const short* vp_ = &Vb[(nt * 16 + lcol) * VSTR + quad * 8];       \
            const bf16x8 v0_ = ldfrag(vp_);                                   \
            const bf16x8 v1_ = ldfrag(vp_ + 32);                              \
            oACC[nt] = __builtin_amdgcn_mfma_f32_16x16x32_bf16(ap0_, v0_, oACC[nt], 0, 0, 0); \
            oACC[nt] = __builtin_amdgcn_mfma_f32_16x16x32_bf16(ap1_, v1_, oACC[nt], 0, 0, 0); \
        }                                                                     \
        __builtin_amdgcn_s_setprio(0);                                        \
    } while (0)

    PREFETCH(0);
    STAGE(Kl[0], Vt[0]);
    PREFETCH(1);
    __syncthreads();

    for (int tile = 0; tile < nb; ++tile) {
        const int cur = tile & 1;
        const short* Kb = Kl[cur];
        const short* Vb = Vt[cur];
        const bool doA = (tile < na);

        // ---- phase B (long q-tile), then phase A (short q-tile) ----
        QTILE_PHASE(aqB0, aqB1, oB, lpB, tile == nb - 1);
        if (doA) QTILE_PHASE(aqA0, aqA1, oA, lpA, tile == na - 1);

        // ---- stage next tile into other buffer; prefetch tile+2 ----
        if (tile + 1 < nb) {
            STAGE(Kl[cur ^ 1], Vt[cur ^ 1]);
            if (tile + 2 < nb) PREFETCH(tile + 2);
        }
        __syncthreads();
    }

    // ---- epilogue: l lives per-lane for q=lcol; reduce across quads only ----
    lpA += __shfl_xor(lpA, 16, 64);
    lpA += __shfl_xor(lpA, 32, 64);
    lpB += __shfl_xor(lpB, 16, 64);
    lpB += __shfl_xor(lpB, 32, 64);
    #pragma unroll
    for (int r = 0; r < 4; ++r) {
        // O rows this lane stores are q = row_l + r; their l is held by lane
        // with lcol = quad*4+r (any quad after the reduce -> use lane quad*4+r)
        const float invA = 1.0f / __shfl(lpA, quad * 4 + r, 64);
        const float invB = 1.0f / __shfl(lpB, quad * 4 + r, 64);
        float* opA = Oh + (size_t)(q0a + row_l + r) * D_DIM;
        float* opB = Oh + (size_t)(q0b + row_l + r) * D_DIM;
        #pragma unroll
        for (int nt = 0; nt < 4; ++nt) {
            opA[nt * 16 + lcol] = oA[nt][r] * invA;
            opB[nt * 16 + lcol] = oB[nt][r] * invB;
        }
    }
}

extern "C" void kernel_launch(void* const* d_in, const int* in_sizes, int n_in,
                              void* d_out, int out_size, void* d_ws, size_t ws_size,
                              hipStream_t stream) {
    const float* Q = (const float*)d_in[0];
    const float* K = (const float*)d_in[1];
    const float* V = (const float*)d_in[2];
    float*       O = (float*)d_out;
    dim3 grid(S_LEN / BM / 2, 4 * 16);   // 16 complementary q-pairs x 64 heads
    fattn_kernel<<<grid, 256, 0, stream>>>(Q, K, V, O);
}

// Round 3
// 226.714 us; speedup vs baseline: 1.3695x; 1.2041x over previous
//
#include <hip/hip_runtime.h>

// Causal flash attention fwd: B=4,H=16,S=2048,D=64. fp32 I/O, bf16 MFMA compute.
// MFMA 16x16x32 bf16. Layouts (HW-verified, learn_hip m89/m91/m120):
//   A[m=lane&15][k=quad*8+j], B[k=quad*8+j][n=lane&15],
//   C/D: col=lane&15, row=quad*4+reg.
// R7: (a) launch_bounds(256,3): R6 at (256,4) still spilled ~1 dword/iter
// (WRITE_SIZE 58.4 MB vs 33.5 MB O); 170-reg cap kills spills and measured
// occupancy was only 2.7 blocks/CU anyway. (b) shared-fragment combined phase
// restored (R5 structure): K frags feed both A+B QK MFMAs, V frags feed both
// PV chains -> LDS reads halve (144->80 KB/block-iter); fits spill-free in
// 170 regs (peak ~150). (c) prefetch kept as RAW float4 (32 regs), bf16 pack
// moved into STAGE, and STAGE moved to iteration START: global loads issue
// early in iter t, consumed early in iter t+1 -> full compute phase of latency
// coverage; staging ds_writes overlap QK MFMAs instead of stalling pre-barrier.
// Retained: swapped QK^T with in-register P (pi/sigma kv reorder, zero LDS for
// P), complementary q-tile pairing (uniform 33 phases/block), double-buffered
// K/V LDS, ONE barrier/tile, T5 setprio around MFMA clusters.

typedef short bf16x4 __attribute__((ext_vector_type(4)));
typedef short bf16x8 __attribute__((ext_vector_type(8)));
typedef float f32x4  __attribute__((ext_vector_type(4)));

#define S_LEN 2048
#define D_DIM 64
#define BM 64
#define BN 64
#define KSTR 68
#define VSTR 68
#define SC_LOG2E 0.18033688011112042f   // (1/8) * log2(e)

// pack two fp32 -> bf16x2 dword by truncation (1 v_perm_b32)
__device__ __forceinline__ unsigned pk2(float lo, float hi) {
    return __builtin_amdgcn_perm(__builtin_bit_cast(unsigned, hi),
                                 __builtin_bit_cast(unsigned, lo), 0x07060302u);
}

__device__ __forceinline__ bf16x8 ldfrag(const short* p) {
    bf16x4 lo = *(const bf16x4*)(p);
    bf16x4 hi = *(const bf16x4*)(p + 4);
    bf16x8 r;
    r[0] = lo[0]; r[1] = lo[1]; r[2] = lo[2]; r[3] = lo[3];
    r[4] = hi[0]; r[5] = hi[1]; r[6] = hi[2]; r[7] = hi[3];
    return r;
}

__device__ __forceinline__ bf16x8 mk8(unsigned u0, unsigned u1, unsigned u2, unsigned u3) {
    union { unsigned u[4]; bf16x8 v; } r;
    r.u[0] = u0; r.u[1] = u1; r.u[2] = u2; r.u[3] = u3;
    return r.v;
}

__global__ __launch_bounds__(256, 3) void fattn_kernel(
    const float* __restrict__ Q, const float* __restrict__ K,
    const float* __restrict__ V, float* __restrict__ O)
{
    __shared__ short Kl[2][BN * KSTR];        // 17408 B
    __shared__ short Vt[2][D_DIM * VSTR];     // 17408 B (V transposed [d][sigma(kv)])

    const int t    = threadIdx.x;
    const int wid  = t >> 6;
    const int lane = t & 63;
    const int quad = lane >> 4;
    const int lcol = lane & 15;

    // paired q-tiles: A = blockIdx.x (short), B = 31-blockIdx.x (long)
    const int na  = blockIdx.x + 1;           // 1..16
    const int nb  = 32 - blockIdx.x;          // 32..17  (nb > na always)
    const int q0a = blockIdx.x * BM;
    const int q0b = (31 - blockIdx.x) * BM;

    const int bh = blockIdx.y;
    const size_t base = (size_t)bh * (S_LEN * D_DIM);
    const float* Qh = Q + base;
    const float* Kh = K + base;
    const float* Vh = V + base;
    float*       Oh = O + base;

    // staging coordinates
    const int skv = t >> 2;            // K: row 0..63
    const int sd  = (t & 3) * 16;      // K: 16-col block
    const int vkv = (t & 31) * 2;      // V: row pair
    const int vdd = (t >> 5) * 8;      // V: 8-col block
    // sigma(kv): bit shuffle [c1 c0 Q1 Q0 r1 r0] -> [c1 Q1 Q0 c0 r1 r0]
    const int vkvp = (vkv & 0x23) | ((vkv & 0x0C) << 1) | ((vkv & 0x10) >> 2);

    // ---- Q fragments for both q-tiles (bf16, d = quad*8+j per mfma half) ----
    bf16x8 aqA0, aqA1, aqB0, aqB1;
    {
        const float* qp = Qh + (size_t)(q0a + wid * 16 + lcol) * D_DIM;
        float4 a = *(const float4*)(qp + quad * 8);
        float4 b = *(const float4*)(qp + quad * 8 + 4);
        float4 c = *(const float4*)(qp + 32 + quad * 8);
        float4 d = *(const float4*)(qp + 32 + quad * 8 + 4);
        aqA0 = mk8(pk2(a.x, a.y), pk2(a.z, a.w), pk2(b.x, b.y), pk2(b.z, b.w));
        aqA1 = mk8(pk2(c.x, c.y), pk2(c.z, c.w), pk2(d.x, d.y), pk2(d.z, d.w));
    }
    {
        const float* qp = Qh + (size_t)(q0b + wid * 16 + lcol) * D_DIM;
        float4 a = *(const float4*)(qp + quad * 8);
        float4 b = *(const float4*)(qp + quad * 8 + 4);
        float4 c = *(const float4*)(qp + 32 + quad * 8);
        float4 d = *(const float4*)(qp + 32 + quad * 8 + 4);
        aqB0 = mk8(pk2(a.x, a.y), pk2(a.z, a.w), pk2(b.x, b.y), pk2(b.z, b.w));
        aqB1 = mk8(pk2(c.x, c.y), pk2(c.z, c.w), pk2(d.x, d.y), pk2(d.z, d.w));
    }

    f32x4 oA[4], oB[4];
    #pragma unroll
    for (int nt = 0; nt < 4; ++nt) {
        oA[nt] = f32x4{0.f, 0.f, 0.f, 0.f};
        oB[nt] = f32x4{0.f, 0.f, 0.f, 0.f};
    }
    float lpA = 0.f, lpB = 0.f;        // per-lane row-sum for q = wid*16+lcol
    const int qrel  = wid * 16 + lcol; // q row this lane owns in softmax phase
    const int row_l = wid * 16 + quad * 4;  // q rows this lane owns in O

    // prefetch registers: RAW float4 (packed to bf16 only inside STAGE, one
    // full iteration after issue -> global latency fully covered by compute)
    float4 kr0, kr1, kr2, kr3, vr0, vr1, vr2, vr3;

#define PREFETCH(tl) do {                                                     \
        const float* kp_ = Kh + (size_t)((tl) * BN + skv) * D_DIM + sd;       \
        kr0 = *(const float4*)(kp_);     kr1 = *(const float4*)(kp_ + 4);     \
        kr2 = *(const float4*)(kp_ + 8); kr3 = *(const float4*)(kp_ + 12);    \
        const float* vp_ = Vh + (size_t)((tl) * BN + vkv) * D_DIM + vdd;      \
        vr0 = *(const float4*)(vp_);         vr1 = *(const float4*)(vp_ + 4); \
        vr2 = *(const float4*)(vp_ + D_DIM); vr3 = *(const float4*)(vp_ + D_DIM + 4); \
    } while (0)

#define STAGE(KB, VB) do {                                                    \
        short* kd_ = (KB) + skv * KSTR + sd;                                  \
        *(uint2*)(kd_)      = make_uint2(pk2(kr0.x, kr0.y), pk2(kr0.z, kr0.w)); \
        *(uint2*)(kd_ + 4)  = make_uint2(pk2(kr1.x, kr1.y), pk2(kr1.z, kr1.w)); \
        *(uint2*)(kd_ + 8)  = make_uint2(pk2(kr2.x, kr2.y), pk2(kr2.z, kr2.w)); \
        *(uint2*)(kd_ + 12) = make_uint2(pk2(kr3.x, kr3.y), pk2(kr3.z, kr3.w)); \
        short* vd_ = (VB) + vkvp;                                             \
        *(unsigned*)(vd_ + (vdd + 0) * VSTR) = pk2(vr0.x, vr2.x);             \
        *(unsigned*)(vd_ + (vdd + 1) * VSTR) = pk2(vr0.y, vr2.y);             \
        *(unsigned*)(vd_ + (vdd + 2) * VSTR) = pk2(vr0.z, vr2.z);             \
        *(unsigned*)(vd_ + (vdd + 3) * VSTR) = pk2(vr0.w, vr2.w);             \
        *(unsigned*)(vd_ + (vdd + 4) * VSTR) = pk2(vr1.x, vr3.x);             \
        *(unsigned*)(vd_ + (vdd + 5) * VSTR) = pk2(vr1.y, vr3.y);             \
        *(unsigned*)(vd_ + (vdd + 6) * VSTR) = pk2(vr1.z, vr3.z);             \
        *(unsigned*)(vd_ + (vdd + 7) * VSTR) = pk2(vr1.w, vr3.w);             \
    } while (0)

// softmax + in-register P pack: lane holds e[ct][r] = P[q=lcol][16ct+4quad+r];
// A-frag slot (h, j) needs P[q][pi(32h+8quad+j)] = e[2h+(j>>2)][j&3]  ->
// ap0 = bf16{e[0][0..3], e[1][0..3]},  ap1 = bf16{e[2][0..3], e[3][0..3]}.
#define SOFTMAX_PACK(sS, lp, diag, ap0, ap1) do {                             \
        unsigned pb_[8];                                                      \
        _Pragma("unroll")                                                     \
        for (int ct = 0; ct < 4; ++ct) {                                      \
            float e_[4];                                                      \
            _Pragma("unroll")                                                 \
            for (int r = 0; r < 4; ++r) {                                     \
                float x_ = (sS)[ct][r] * SC_LOG2E;                            \
                if ((diag) && (ct * 16 + quad * 4 + r > qrel))                \
                    x_ = -__builtin_inff();                                   \
                e_[r] = __builtin_amdgcn_exp2f(x_);                           \
                (lp) += e_[r];                                                \
            }                                                                 \
            pb_[2 * ct]     = pk2(e_[0], e_[1]);                              \
            pb_[2 * ct + 1] = pk2(e_[2], e_[3]);                              \
        }                                                                     \
        (ap0) = mk8(pb_[0], pb_[1], pb_[2], pb_[3]);                          \
        (ap1) = mk8(pb_[4], pb_[5], pb_[6], pb_[7]);                          \
    } while (0)

    // prologue: stage tile 0, issue prefetch of tile 1
    PREFETCH(0);
    STAGE(Kl[0], Vt[0]);
    PREFETCH(1);
    __syncthreads();

    for (int tile = 0; tile < nb; ++tile) {
        const int cur = tile & 1;
        const short* Kb = Kl[cur];
        const short* Vb = Vt[cur];
        const bool doA = (tile < na);

        // ---- stage NEXT tile first (prev barrier made cur^1 safe to write);
        //      ds_writes overlap the MFMA compute below; then issue prefetch
        //      for tile+2 (consumed at next iteration's STAGE) ----
        if (tile + 1 < nb) {
            STAGE(Kl[cur ^ 1], Vt[cur ^ 1]);
            if (tile + 2 < nb) PREFETCH(tile + 2);
        }

        // ---- swapped QK^T: S^T = mfma(K_frag, Q_frag); K frags shared A+B ----
        f32x4 sA[4], sB[4];
        __builtin_amdgcn_s_setprio(1);
        #pragma unroll
        for (int ct = 0; ct < 4; ++ct) {
            const short* kp0 = &Kb[(ct * 16 + lcol) * KSTR + quad * 8];
            const bf16x8 b0 = ldfrag(kp0);        // d = quad*8+j       (k half 0)
            const bf16x8 b1 = ldfrag(kp0 + 32);   // d = 32+quad*8+j    (k half 1)
            f32x4 z = f32x4{0.f, 0.f, 0.f, 0.f};
            z = __builtin_amdgcn_mfma_f32_16x16x32_bf16(b0, aqB0, z, 0, 0, 0);
            z = __builtin_amdgcn_mfma_f32_16x16x32_bf16(b1, aqB1, z, 0, 0, 0);
            sB[ct] = z;
            if (doA) {
                f32x4 y = f32x4{0.f, 0.f, 0.f, 0.f};
                y = __builtin_amdgcn_mfma_f32_16x16x32_bf16(b0, aqA0, y, 0, 0, 0);
                y = __builtin_amdgcn_mfma_f32_16x16x32_bf16(b1, aqA1, y, 0, 0, 0);
                sA[ct] = y;
            }
        }
        __builtin_amdgcn_s_setprio(0);

        // ---- softmax numerators, packed straight into PV A-fragments ----
        bf16x8 apA0, apA1, apB0, apB1;
        SOFTMAX_PACK(sB, lpB, tile == nb - 1, apB0, apB1);
        if (doA) SOFTMAX_PACK(sA, lpA, tile == na - 1, apA0, apA1);

        // ---- O += P V : V fragments shared A+B (sigma kv-slot order) ----
        __builtin_amdgcn_s_setprio(1);
        #pragma unroll
        for (int nt = 0; nt < 4; ++nt) {
            const short* vp0 = &Vb[(nt * 16 + lcol) * VSTR + quad * 8];
            const bf16x8 v0 = ldfrag(vp0);
            const bf16x8 v1 = ldfrag(vp0 + 32);
            oB[nt] = __builtin_amdgcn_mfma_f32_16x16x32_bf16(apB0, v0, oB[nt], 0, 0, 0);
            oB[nt] = __builtin_amdgcn_mfma_f32_16x16x32_bf16(apB1, v1, oB[nt], 0, 0, 0);
            if (doA) {
                oA[nt] = __builtin_amdgcn_mfma_f32_16x16x32_bf16(apA0, v0, oA[nt], 0, 0, 0);
                oA[nt] = __builtin_amdgcn_mfma_f32_16x16x32_bf16(apA1, v1, oA[nt], 0, 0, 0);
            }
        }
        __builtin_amdgcn_s_setprio(0);

        __syncthreads();
    }

    // ---- epilogue: l lives per-lane for q=lcol; reduce across quads only ----
    lpA += __shfl_xor(lpA, 16, 64);
    lpA += __shfl_xor(lpA, 32, 64);
    lpB += __shfl_xor(lpB, 16, 64);
    lpB += __shfl_xor(lpB, 32, 64);
    #pragma unroll
    for (int r = 0; r < 4; ++r) {
        // O rows this lane stores are q = row_l + r; their l is held by lane
        // with lcol = quad*4+r (any quad after the reduce -> use lane quad*4+r)
        const float invA = 1.0f / __shfl(lpA, quad * 4 + r, 64);
        const float invB = 1.0f / __shfl(lpB, quad * 4 + r, 64);
        float* opA = Oh + (size_t)(q0a + row_l + r) * D_DIM;
        float* opB = Oh + (size_t)(q0b + row_l + r) * D_DIM;
        #pragma unroll
        for (int nt = 0; nt < 4; ++nt) {
            opA[nt * 16 + lcol] = oA[nt][r] * invA;
            opB[nt * 16 + lcol] = oB[nt][r] * invB;
        }
    }
}

extern "C" void kernel_launch(void* const* d_in, const int* in_sizes, int n_in,
                              void* d_out, int out_size, void* d_ws, size_t ws_size,
                              hipStream_t stream) {
    const float* Q = (const float*)d_in[0];
    const float* K = (const float*)d_in[1];
    const float* V = (const float*)d_in[2];
    float*       O = (float*)d_out;
    dim3 grid(S_LEN / BM / 2, 4 * 16);   // 16 complementary q-pairs x 64 heads
    fattn_kernel<<<grid, 256, 0, stream>>>(Q, K, V, O);
}